// Round 2
// baseline (172.053 us; speedup 1.0000x reference)
//
#include <hip/hip_runtime.h>
#include <math.h>

#define VL 32
#define W  97           // 3*VL + 1
#define NU 50
#define NC 10
#define ND 20
#define FU (NU * W)     // 4850 floats, 19400 B  (8B-aligned per element)
#define FC (NC * W)     //  970 floats,  3880 B
#define FD (ND * W)     // 1940 floats,  7760 B
#define FT (FU + FC + FD) // 7760 floats total = 31040 B LDS

__global__ __launch_bounds__(128) void ffm_kernel(
    const float* __restrict__ user,
    const float* __restrict__ ctx,
    const float* __restrict__ doc,
    float* __restrict__ out)
{
    const int b = blockIdx.x;
    const int t = threadIdx.x;          // 0..127

    __shared__ float buf[FT];           // staged raw data; later reused for field sums
    __shared__ float s_red[2];

    // ---- Stage all three field chunks into LDS with linear float2 loads.
    // Chunk byte sizes (19400/3880/7760) are all multiples of 8, and base
    // pointers are 256B-aligned, so float2 is always safe.
    {
        const float2* __restrict__ src = (const float2*)(user + (size_t)b * FU);
        float2* dst = (float2*)buf;
        #pragma unroll
        for (int i = 0; i < (FU / 2 + 127) / 128; ++i) {
            int idx = t + i * 128;
            if (idx < FU / 2) dst[idx] = src[idx];
        }
    }
    {
        const float2* __restrict__ src = (const float2*)(ctx + (size_t)b * FC);
        float2* dst = (float2*)(buf + FU);
        #pragma unroll
        for (int i = 0; i < (FC / 2 + 127) / 128; ++i) {
            int idx = t + i * 128;
            if (idx < FC / 2) dst[idx] = src[idx];
        }
    }
    {
        const float2* __restrict__ src = (const float2*)(doc + (size_t)b * FD);
        float2* dst = (float2*)(buf + FU + FC);
        #pragma unroll
        for (int i = 0; i < (FD / 2 + 127) / 128; ++i) {
            int idx = t + i * 128;
            if (idx < FD / 2) dst[idx] = src[idx];
        }
    }
    __syncthreads();

    // ---- Per-column sums / sum-of-squares from LDS (consecutive lanes ->
    // consecutive addresses -> conflict-free ds_read_b32).
    float su = 0.f, sc = 0.f, sd = 0.f;
    float squ = 0.f, sqc = 0.f, sqd = 0.f;
    if (t < W) {
        #pragma unroll
        for (int r = 0; r < NU; ++r) {
            float x = buf[r * W + t];
            su += x; squ += x * x;
        }
        #pragma unroll
        for (int r = 0; r < NC; ++r) {
            float x = buf[FU + r * W + t];
            sc += x; sqc += x * x;
        }
        #pragma unroll
        for (int r = 0; r < ND; ++r) {
            float x = buf[FU + FC + r * W + t];
            sd += x; sqd += x * x;
        }
    }
    __syncthreads();   // everyone done reading raw data; buf can be reused

    if (t < W) {
        buf[t]         = su;   // s_su
        buf[W + t]     = sc;   // s_sc
        buf[2 * W + t] = sd;   // s_sd
    }
    __syncthreads();

    // ---- Per-thread partial of z.
    float partial = 0.f;
    if (t < VL)                  partial -= 0.5f * squ;   // user sq cols 0:VL
    else if (t < 2 * VL)         partial -= 0.5f * sqc;   // ctx  sq cols VL:2VL
    else if (t < 3 * VL)         partial -= 0.5f * sqd;   // doc  sq cols 2VL:3VL

    if (t < VL) {
        float a0 = buf[t];                 // su[t]
        float a1 = buf[W + VL + t];        // sc[VL+t]
        float a2 = buf[2 * W + 2 * VL + t];// sd[2VL+t]
        partial += 0.5f * (a0 * a0 + a1 * a1 + a2 * a2);
        partial += buf[VL + t]         * buf[W + t];          // su[VL+t]  * sc[t]
        partial += buf[2 * VL + t]     * buf[2 * W + t];      // su[2VL+t] * sd[t]
        partial += buf[W + 2 * VL + t] * buf[2 * W + VL + t]; // sc[2VL+t] * sd[VL+t]
    }
    if (t == 3 * VL)
        partial += buf[t] + buf[W + t] + buf[2 * W + t];      // linear/bias col

    // ---- Block reduction: wave64 shuffle, then 2-entry LDS.
    #pragma unroll
    for (int off = 32; off > 0; off >>= 1)
        partial += __shfl_down(partial, off, 64);
    if ((t & 63) == 0)
        s_red[t >> 6] = partial;
    __syncthreads();
    if (t == 0) {
        float z = s_red[0] + s_red[1];
        out[b] = 1.0f / (1.0f + expf(-z));
    }
}

extern "C" void kernel_launch(void* const* d_in, const int* in_sizes, int n_in,
                              void* d_out, int out_size, void* d_ws, size_t ws_size,
                              hipStream_t stream) {
    const float* user = (const float*)d_in[0];
    const float* ctx  = (const float*)d_in[1];
    const float* doc  = (const float*)d_in[2];
    float* out = (float*)d_out;

    const int B = out_size;   // 16384 batch rows, one per output element
    ffm_kernel<<<B, 128, 0, stream>>>(user, ctx, doc, out);
}

// Round 3
// 86.137 us; speedup vs baseline: 1.9974x; 1.9974x over previous
//
#include <hip/hip_runtime.h>
#include <math.h>

#define VL 32
#define W  97           // 3*VL + 1
#define NU 50
#define NC 10
#define ND 20

__global__ __launch_bounds__(128) void ffm_kernel(
    const float* __restrict__ user,
    const float* __restrict__ ctx,
    const float* __restrict__ doc,
    float* __restrict__ out)
{
    const int b = blockIdx.x;
    const int j = threadIdx.x;          // 0..127; active for j < 97

    __shared__ float s_su[W];
    __shared__ float s_sc[W];
    __shared__ float s_sd[W];
    __shared__ float s_red[2];

    float su = 0.f, sc = 0.f, sd = 0.f;
    float squ = 0.f, sqc = 0.f, sqd = 0.f;

    if (j < W) {
        // ---- user: load all 50 rows into registers first (deep VMEM clause,
        // ~50 loads in flight), then accumulate. Static indexing only.
        {
            const float* up = user + (size_t)b * NU * W + j;
            float x[NU];
            #pragma unroll
            for (int r = 0; r < NU; ++r) x[r] = up[(size_t)r * W];
            #pragma unroll
            for (int r = 0; r < NU; ++r) { su += x[r]; squ += x[r] * x[r]; }
        }
        // ---- ctx: 10 rows
        {
            const float* cp = ctx + (size_t)b * NC * W + j;
            float x[NC];
            #pragma unroll
            for (int r = 0; r < NC; ++r) x[r] = cp[(size_t)r * W];
            #pragma unroll
            for (int r = 0; r < NC; ++r) { sc += x[r]; sqc += x[r] * x[r]; }
        }
        // ---- doc: 20 rows
        {
            const float* dp = doc + (size_t)b * ND * W + j;
            float x[ND];
            #pragma unroll
            for (int r = 0; r < ND; ++r) x[r] = dp[(size_t)r * W];
            #pragma unroll
            for (int r = 0; r < ND; ++r) { sd += x[r]; sqd += x[r] * x[r]; }
        }
        s_su[j] = su;
        s_sc[j] = sc;
        s_sd[j] = sd;
    }
    __syncthreads();

    // ---- Per-thread partial of z.
    float partial = 0.f;
    if (j < VL)                  partial -= 0.5f * squ;   // user sq cols 0:VL
    else if (j < 2 * VL)         partial -= 0.5f * sqc;   // ctx  sq cols VL:2VL
    else if (j < 3 * VL)         partial -= 0.5f * sqd;   // doc  sq cols 2VL:3VL

    if (j < VL) {
        float a0 = s_su[j];
        float a1 = s_sc[VL + j];
        float a2 = s_sd[2 * VL + j];
        partial += 0.5f * (a0 * a0 + a1 * a1 + a2 * a2);
        partial += s_su[VL + j]     * s_sc[j];            // dot(su[VL:2VL],  sc[0:VL])
        partial += s_su[2 * VL + j] * s_sd[j];            // dot(su[2VL:3VL], sd[0:VL])
        partial += s_sc[2 * VL + j] * s_sd[VL + j];       // dot(sc[2VL:3VL], sd[VL:2VL])
    }
    if (j == 3 * VL)
        partial += s_su[j] + s_sc[j] + s_sd[j];           // linear/bias column

    // ---- Block reduction: wave64 shuffle, then 2-entry LDS.
    #pragma unroll
    for (int off = 32; off > 0; off >>= 1)
        partial += __shfl_down(partial, off, 64);
    if ((j & 63) == 0)
        s_red[j >> 6] = partial;
    __syncthreads();
    if (j == 0) {
        float z = s_red[0] + s_red[1];
        out[b] = 1.0f / (1.0f + expf(-z));
    }
}

extern "C" void kernel_launch(void* const* d_in, const int* in_sizes, int n_in,
                              void* d_out, int out_size, void* d_ws, size_t ws_size,
                              hipStream_t stream) {
    const float* user = (const float*)d_in[0];
    const float* ctx  = (const float*)d_in[1];
    const float* doc  = (const float*)d_in[2];
    float* out = (float*)d_out;

    const int B = out_size;   // 16384 batch rows, one per output element
    ffm_kernel<<<B, 128, 0, stream>>>(user, ctx, doc, out);
}